// Round 1
// baseline (453.410 us; speedup 1.0000x reference)
//
#include <hip/hip_runtime.h>
#include <hip/hip_bf16.h>

// Problem constants
#define B_    64
#define T_    200
#define CIN_  80
#define C_    1024
#define M_    (B_ * T_)   // 12800 rows for both GEMMs
#define BCEL  (B_ * C_)   // 65536 parallel LIF lanes

// ---------------------------------------------------------------------------
// Tiled f32 GEMM: C[M,N] = A[M,K] * B[N,K]^T (+ bias[N] if non-null)
// BM=BN=64, BK=16, 256 threads, 4x4 accum per thread.
// ---------------------------------------------------------------------------
__global__ __launch_bounds__(256) void gemm_abt(
    const float* __restrict__ A, const float* __restrict__ Bm,
    const float* __restrict__ bias, float* __restrict__ C,
    int M, int N, int K) {
  __shared__ float As[16][64];
  __shared__ float Bs[16][64];
  const int tid = threadIdx.x;
  const int tx = tid & 15;        // N sub-tile
  const int ty = tid >> 4;        // M sub-tile
  const int m0 = blockIdx.x * 64;
  const int n0 = blockIdx.y * 64;
  const int lr = tid >> 2;        // 0..63 tile row for loads
  const int lc = (tid & 3) * 4;   // 0,4,8,12 k-offset for loads

  float acc[4][4] = {{0.f, 0.f, 0.f, 0.f}, {0.f, 0.f, 0.f, 0.f},
                     {0.f, 0.f, 0.f, 0.f}, {0.f, 0.f, 0.f, 0.f}};

  const float* Aro = A + (size_t)(m0 + lr) * K + lc;
  const float* Bro = Bm + (size_t)(n0 + lr) * K + lc;

  for (int k0 = 0; k0 < K; k0 += 16) {
    float4 a4 = *(const float4*)(Aro + k0);
    float4 b4 = *(const float4*)(Bro + k0);
    __syncthreads();
    As[lc + 0][lr] = a4.x; As[lc + 1][lr] = a4.y;
    As[lc + 2][lr] = a4.z; As[lc + 3][lr] = a4.w;
    Bs[lc + 0][lr] = b4.x; Bs[lc + 1][lr] = b4.y;
    Bs[lc + 2][lr] = b4.z; Bs[lc + 3][lr] = b4.w;
    __syncthreads();
#pragma unroll
    for (int kk = 0; kk < 16; ++kk) {
      float4 av = *(const float4*)&As[kk][ty * 4];
      float4 bv = *(const float4*)&Bs[kk][tx * 4];
      acc[0][0] = fmaf(av.x, bv.x, acc[0][0]);
      acc[0][1] = fmaf(av.x, bv.y, acc[0][1]);
      acc[0][2] = fmaf(av.x, bv.z, acc[0][2]);
      acc[0][3] = fmaf(av.x, bv.w, acc[0][3]);
      acc[1][0] = fmaf(av.y, bv.x, acc[1][0]);
      acc[1][1] = fmaf(av.y, bv.y, acc[1][1]);
      acc[1][2] = fmaf(av.y, bv.z, acc[1][2]);
      acc[1][3] = fmaf(av.y, bv.w, acc[1][3]);
      acc[2][0] = fmaf(av.z, bv.x, acc[2][0]);
      acc[2][1] = fmaf(av.z, bv.y, acc[2][1]);
      acc[2][2] = fmaf(av.z, bv.z, acc[2][2]);
      acc[2][3] = fmaf(av.z, bv.w, acc[2][3]);
      acc[3][0] = fmaf(av.w, bv.x, acc[3][0]);
      acc[3][1] = fmaf(av.w, bv.y, acc[3][1]);
      acc[3][2] = fmaf(av.w, bv.z, acc[3][2]);
      acc[3][3] = fmaf(av.w, bv.w, acc[3][3]);
    }
  }

  float bj[4] = {0.f, 0.f, 0.f, 0.f};
  if (bias) {
#pragma unroll
    for (int j = 0; j < 4; ++j) bj[j] = bias[n0 + tx * 4 + j];
  }
#pragma unroll
  for (int i = 0; i < 4; ++i) {
    int m = m0 + ty * 4 + i;
    float4 o4;
    o4.x = acc[i][0] + bj[0];
    o4.y = acc[i][1] + bj[1];
    o4.z = acc[i][2] + bj[2];
    o4.w = acc[i][3] + bj[3];
    *(float4*)&C[(size_t)m * N + n0 + tx * 4] = o4;
  }
}

// ---------------------------------------------------------------------------
// Depthwise conv (K=7, same pad) + BN1 (eval) + LIF1 scan.
// One thread per (b, o); p is [B,T,C]; writes spikes s1 to out [T,B,C].
// ---------------------------------------------------------------------------
__global__ __launch_bounds__(256) void dw_bn_lif(
    const float* __restrict__ p, const float* __restrict__ dw_w,
    const float* __restrict__ dw_b, const float* __restrict__ gam,
    const float* __restrict__ bet, const float* __restrict__ mu,
    const float* __restrict__ var, float* __restrict__ s1) {
  int gid = blockIdx.x * blockDim.x + threadIdx.x;
  int b = gid >> 10;
  int o = gid & 1023;

  float w[7];
#pragma unroll
  for (int k = 0; k < 7; ++k) w[k] = dw_w[o * 7 + k];
  float db = dw_b[o];
  float inv = (float)((double)gam[o] / sqrt((double)var[o] + 1e-5));
  float add = (float)((double)bet[o] - (double)mu[o] * (double)inv);

  const float* pp = p + (size_t)b * T_ * C_ + o;
  float r[7];
  r[0] = 0.f; r[1] = 0.f; r[2] = 0.f;
#pragma unroll
  for (int i = 0; i < 4; ++i) r[3 + i] = pp[(size_t)i * C_];

  float v = 0.f;
  size_t obase = (size_t)b * C_ + o;
  for (int t = 0; t < T_; ++t) {
    float u = db;
#pragma unroll
    for (int k = 0; k < 7; ++k) u = fmaf(w[k], r[k], u);
    u = fmaf(u, inv, add);
    v = fmaf(0.5f, v, u);                 // v = v - (v-0)/2 + u (exact)
    bool sp = (v - 1.0f) >= 0.0f;         // spike_fn(v - V_TH)
    s1[obase + (size_t)t * BCEL] = sp ? 1.0f : 0.0f;
    v = sp ? 0.0f : v;                    // hard reset
#pragma unroll
    for (int k = 0; k < 6; ++k) r[k] = r[k + 1];
    int tn = t + 4;
    r[6] = (tn < T_) ? pp[(size_t)tn * C_] : 0.f;
  }
}

// ---------------------------------------------------------------------------
// BN2 (eval) + LIF2 scan + residual add, in-place on out (which holds s1).
// y is [T,B,C].
// ---------------------------------------------------------------------------
__global__ __launch_bounds__(256) void bn_lif_add(
    const float* __restrict__ y, const float* __restrict__ gam,
    const float* __restrict__ bet, const float* __restrict__ mu,
    const float* __restrict__ var, float* __restrict__ out) {
  int gid = blockIdx.x * blockDim.x + threadIdx.x;
  int b = gid >> 10;
  int o = gid & 1023;

  float inv = (float)((double)gam[o] / sqrt((double)var[o] + 1e-5));
  float add = (float)((double)bet[o] - (double)mu[o] * (double)inv);

  float v = 0.f;
  size_t base = (size_t)b * C_ + o;
  for (int t = 0; t < T_; ++t) {
    size_t idx = base + (size_t)t * BCEL;
    float u = fmaf(y[idx], inv, add);
    v = fmaf(0.5f, v, u);
    bool sp = (v - 1.0f) >= 0.0f;
    float s1v = out[idx];
    out[idx] = (sp ? 1.0f : 0.0f) + s1v;
    v = sp ? 0.0f : v;
  }
}

// ---------------------------------------------------------------------------
extern "C" void kernel_launch(void* const* d_in, const int* in_sizes, int n_in,
                              void* d_out, int out_size, void* d_ws,
                              size_t ws_size, hipStream_t stream) {
  const float* x     = (const float*)d_in[0];   // [B,T,Cin]
  const float* pw_w  = (const float*)d_in[1];   // [C,Cin]
  const float* pw_b  = (const float*)d_in[2];   // [C]
  const float* dw_w  = (const float*)d_in[3];   // [C,7]
  const float* dw_b  = (const float*)d_in[4];   // [C]
  const float* bn1g  = (const float*)d_in[5];
  const float* bn1b  = (const float*)d_in[6];
  const float* bn1m  = (const float*)d_in[7];
  const float* bn1v  = (const float*)d_in[8];
  const float* lin_w = (const float*)d_in[9];   // [C,C]
  const float* bn2g  = (const float*)d_in[10];
  const float* bn2b  = (const float*)d_in[11];
  const float* bn2m  = (const float*)d_in[12];
  const float* bn2v  = (const float*)d_in[13];
  float* out = (float*)d_out;                   // [T,B,C]; holds s1 mid-pipe
  float* p   = (float*)d_ws;                    // [B,T,C] (52 MB), reused as y

  dim3 gemm_grid(M_ / 64, C_ / 64);

  // 1) pointwise conv as GEMM: p[(b,t),o] = x[(b,t),:] . pw_w[o,:] + pw_b[o]
  gemm_abt<<<gemm_grid, 256, 0, stream>>>(x, pw_w, pw_b, p, M_, C_, CIN_);

  // 2) depthwise + BN1 + LIF1 -> s1 in d_out as [T,B,C]
  dw_bn_lif<<<BCEL / 256, 256, 0, stream>>>(p, dw_w, dw_b, bn1g, bn1b, bn1m,
                                            bn1v, out);

  // 3) linear: y[(t,b),o] = s1[(t,b),:] . lin_w[o,:]   (y reuses ws)
  gemm_abt<<<gemm_grid, 256, 0, stream>>>(out, lin_w, nullptr, p, M_, C_, C_);

  // 4) BN2 + LIF2 + residual, in place on d_out
  bn_lif_add<<<BCEL / 256, 256, 0, stream>>>(p, bn2g, bn2b, bn2m, bn2v, out);
}

// Round 2
// 231.731 us; speedup vs baseline: 1.9566x; 1.9566x over previous
//
#include <hip/hip_runtime.h>
#include <hip/hip_bf16.h>
#include <stdint.h>

// Problem constants
#define B_    64
#define T_    200
#define CIN_  80
#define C_    1024
#define M_    (B_ * T_)   // 12800
#define BCEL  (B_ * C_)   // 65536

typedef __attribute__((ext_vector_type(4))) float f32x4;
typedef __attribute__((ext_vector_type(8))) short bf16x8;  // 8 bf16 in 4 VGPRs

// ---------------------------------------------------------------------------
// f32 GEMM (vector ALU) for the pointwise conv: C[M,N] = A[M,K]*B[N,K]^T + bias
// ---------------------------------------------------------------------------
__global__ __launch_bounds__(256) void gemm_abt(
    const float* __restrict__ A, const float* __restrict__ Bm,
    const float* __restrict__ bias, float* __restrict__ C,
    int M, int N, int K) {
  __shared__ float As[16][64];
  __shared__ float Bs[16][64];
  const int tid = threadIdx.x;
  const int tx = tid & 15;
  const int ty = tid >> 4;
  const int m0 = blockIdx.x * 64;
  const int n0 = blockIdx.y * 64;
  const int lr = tid >> 2;
  const int lc = (tid & 3) * 4;

  float acc[4][4] = {{0.f,0.f,0.f,0.f},{0.f,0.f,0.f,0.f},
                     {0.f,0.f,0.f,0.f},{0.f,0.f,0.f,0.f}};
  const float* Aro = A + (size_t)(m0 + lr) * K + lc;
  const float* Bro = Bm + (size_t)(n0 + lr) * K + lc;

  for (int k0 = 0; k0 < K; k0 += 16) {
    float4 a4 = *(const float4*)(Aro + k0);
    float4 b4 = *(const float4*)(Bro + k0);
    __syncthreads();
    As[lc + 0][lr] = a4.x; As[lc + 1][lr] = a4.y;
    As[lc + 2][lr] = a4.z; As[lc + 3][lr] = a4.w;
    Bs[lc + 0][lr] = b4.x; Bs[lc + 1][lr] = b4.y;
    Bs[lc + 2][lr] = b4.z; Bs[lc + 3][lr] = b4.w;
    __syncthreads();
#pragma unroll
    for (int kk = 0; kk < 16; ++kk) {
      float4 av = *(const float4*)&As[kk][ty * 4];
      float4 bv = *(const float4*)&Bs[kk][tx * 4];
      acc[0][0] = fmaf(av.x, bv.x, acc[0][0]);
      acc[0][1] = fmaf(av.x, bv.y, acc[0][1]);
      acc[0][2] = fmaf(av.x, bv.z, acc[0][2]);
      acc[0][3] = fmaf(av.x, bv.w, acc[0][3]);
      acc[1][0] = fmaf(av.y, bv.x, acc[1][0]);
      acc[1][1] = fmaf(av.y, bv.y, acc[1][1]);
      acc[1][2] = fmaf(av.y, bv.z, acc[1][2]);
      acc[1][3] = fmaf(av.y, bv.w, acc[1][3]);
      acc[2][0] = fmaf(av.z, bv.x, acc[2][0]);
      acc[2][1] = fmaf(av.z, bv.y, acc[2][1]);
      acc[2][2] = fmaf(av.z, bv.z, acc[2][2]);
      acc[2][3] = fmaf(av.z, bv.w, acc[2][3]);
      acc[3][0] = fmaf(av.w, bv.x, acc[3][0]);
      acc[3][1] = fmaf(av.w, bv.y, acc[3][1]);
      acc[3][2] = fmaf(av.w, bv.z, acc[3][2]);
      acc[3][3] = fmaf(av.w, bv.w, acc[3][3]);
    }
  }

  float bj[4] = {0.f, 0.f, 0.f, 0.f};
  if (bias) {
#pragma unroll
    for (int j = 0; j < 4; ++j) bj[j] = bias[n0 + tx * 4 + j];
  }
#pragma unroll
  for (int i = 0; i < 4; ++i) {
    int m = m0 + ty * 4 + i;
    float4 o4;
    o4.x = acc[i][0] + bj[0];
    o4.y = acc[i][1] + bj[1];
    o4.z = acc[i][2] + bj[2];
    o4.w = acc[i][3] + bj[3];
    *(float4*)&C[(size_t)m * N + n0 + tx * 4] = o4;
  }
}

// ---------------------------------------------------------------------------
// Depthwise conv (K=7, same pad) + BN1 + LIF1 scan.  p:[B,T,C] -> s1:[T,B,C] f32
// ---------------------------------------------------------------------------
__global__ __launch_bounds__(256) void dw_bn_lif(
    const float* __restrict__ p, const float* __restrict__ dw_w,
    const float* __restrict__ dw_b, const float* __restrict__ gam,
    const float* __restrict__ bet, const float* __restrict__ mu,
    const float* __restrict__ var, float* __restrict__ s1) {
  int gid = blockIdx.x * blockDim.x + threadIdx.x;
  int b = gid >> 10;
  int o = gid & 1023;

  float w[7];
#pragma unroll
  for (int k = 0; k < 7; ++k) w[k] = dw_w[o * 7 + k];
  float db = dw_b[o];
  float inv = (float)((double)gam[o] / sqrt((double)var[o] + 1e-5));
  float add = (float)((double)bet[o] - (double)mu[o] * (double)inv);

  const float* pp = p + (size_t)b * T_ * C_ + o;
  float r[7];
  r[0] = 0.f; r[1] = 0.f; r[2] = 0.f;
#pragma unroll
  for (int i = 0; i < 4; ++i) r[3 + i] = pp[(size_t)i * C_];

  float v = 0.f;
  size_t obase = (size_t)b * C_ + o;
  for (int t = 0; t < T_; ++t) {
    float u = db;
#pragma unroll
    for (int k = 0; k < 7; ++k) u = fmaf(w[k], r[k], u);
    u = fmaf(u, inv, add);
    v = fmaf(0.5f, v, u);
    bool sp = (v - 1.0f) >= 0.0f;
    s1[obase + (size_t)t * BCEL] = sp ? 1.0f : 0.0f;
    v = sp ? 0.0f : v;
#pragma unroll
    for (int k = 0; k < 6; ++k) r[k] = r[k + 1];
    int tn = t + 4;
    r[6] = (tn < T_) ? pp[(size_t)tn * C_] : 0.f;
  }
}

// ---------------------------------------------------------------------------
// f32 -> bf16 copy (spikes are exactly 0.0/1.0; truncation is exact)
// ---------------------------------------------------------------------------
__global__ __launch_bounds__(256) void cvt_bf16(
    const float* __restrict__ in, __hip_bfloat16* __restrict__ out, int n) {
  int i = (blockIdx.x * 256 + threadIdx.x) * 8;
  if (i >= n) return;
  const float4* p4 = (const float4*)(in + i);
  float4 a = p4[0], b = p4[1];
  union { ushort u[8]; uint4 q; } o;
  o.u[0] = (ushort)(__float_as_uint(a.x) >> 16);
  o.u[1] = (ushort)(__float_as_uint(a.y) >> 16);
  o.u[2] = (ushort)(__float_as_uint(a.z) >> 16);
  o.u[3] = (ushort)(__float_as_uint(a.w) >> 16);
  o.u[4] = (ushort)(__float_as_uint(b.x) >> 16);
  o.u[5] = (ushort)(__float_as_uint(b.y) >> 16);
  o.u[6] = (ushort)(__float_as_uint(b.z) >> 16);
  o.u[7] = (ushort)(__float_as_uint(b.w) >> 16);
  *(uint4*)((ushort*)out + i) = o.q;
}

// ---------------------------------------------------------------------------
// Residual 3-way bf16 split of f32 weights: w = w0 + w1 + w2 (to ~2^-26 rel)
// ---------------------------------------------------------------------------
__global__ __launch_bounds__(256) void split_w(
    const float* __restrict__ w, __hip_bfloat16* __restrict__ w0,
    __hip_bfloat16* __restrict__ w1, __hip_bfloat16* __restrict__ w2, int n) {
  int i = blockIdx.x * 256 + threadIdx.x;
  if (i >= n) return;
  float x = w[i];
  __hip_bfloat16 h0 = __float2bfloat16(x);
  float r1 = x - __bfloat162float(h0);
  __hip_bfloat16 h1 = __float2bfloat16(r1);
  float r2 = r1 - __bfloat162float(h1);
  __hip_bfloat16 h2 = __float2bfloat16(r2);
  w0[i] = h0; w1[i] = h1; w2[i] = h2;
}

// ---------------------------------------------------------------------------
// MFMA bf16 GEMM: y[M,N] = S[M,K] * (B0+B1+B2)[N,K]^T
// 128x128 tile, BK=32, 4 waves (2x2), global_load_lds width-16 staging.
// One A tile staged per K-step, shared across the 3 split B tiles.
// ---------------------------------------------------------------------------
#define BM 128
#define BN 128
#define BKg 32

__global__ __launch_bounds__(256) void gemm_mfma3(
    const __hip_bfloat16* __restrict__ A,
    const __hip_bfloat16* __restrict__ B0,
    const __hip_bfloat16* __restrict__ B1,
    const __hip_bfloat16* __restrict__ B2,
    float* __restrict__ Cout) {
  const int K = C_;
  const int N = C_;
  __shared__ __align__(16) __hip_bfloat16 Ash[BM * BKg];      // 8 KB
  __shared__ __align__(16) __hip_bfloat16 Bsh[3][BN * BKg];   // 24 KB

  const int tid  = threadIdx.x;
  const int lane = tid & 63;
  const int wm = ((tid >> 6) >> 1) * 64;   // wave row offset
  const int wn = ((tid >> 6) & 1) * 64;    // wave col offset

  // XCD-aware swizzle: 800 blocks -> 100 contiguous per XCD, n fastest inside
  int lin = blockIdx.x;
  int qq = gridDim.x >> 3;                 // 100
  int wg = (lin & 7) * qq + (lin >> 3);
  const int m0 = (wg >> 3) * BM;
  const int n0 = (wg & 7) * BN;

  // staging chunk for this thread: c = tid + 256*i; row=c>>2, k8=(c&3)*8
  const int r0 = tid >> 2, kc0 = (tid & 3) * 8;
  const int r1 = (tid + 256) >> 2, kc1 = ((tid + 256) & 3) * 8;

  f32x4 acc[4][4] = {};

  for (int k0 = 0; k0 < K; k0 += BKg) {
    __syncthreads();
    // ---- stage A tile ----
    {
      const __hip_bfloat16* s0 = A + (size_t)(m0 + r0) * K + k0 + kc0;
      const __hip_bfloat16* s1p = A + (size_t)(m0 + r1) * K + k0 + kc1;
      __builtin_amdgcn_global_load_lds(
          (const __attribute__((address_space(1))) uint32_t*)s0,
          (__attribute__((address_space(3))) uint32_t*)&Ash[tid * 8], 16, 0, 0);
      __builtin_amdgcn_global_load_lds(
          (const __attribute__((address_space(1))) uint32_t*)s1p,
          (__attribute__((address_space(3))) uint32_t*)&Ash[(tid + 256) * 8], 16, 0, 0);
    }
    // ---- stage 3 B tiles ----
#pragma unroll
    for (int s = 0; s < 3; ++s) {
      const __hip_bfloat16* Bp = (s == 0) ? B0 : (s == 1) ? B1 : B2;
      const __hip_bfloat16* s0 = Bp + (size_t)(n0 + r0) * K + k0 + kc0;
      const __hip_bfloat16* s1p = Bp + (size_t)(n0 + r1) * K + k0 + kc1;
      __builtin_amdgcn_global_load_lds(
          (const __attribute__((address_space(1))) uint32_t*)s0,
          (__attribute__((address_space(3))) uint32_t*)&Bsh[s][tid * 8], 16, 0, 0);
      __builtin_amdgcn_global_load_lds(
          (const __attribute__((address_space(1))) uint32_t*)s1p,
          (__attribute__((address_space(3))) uint32_t*)&Bsh[s][(tid + 256) * 8], 16, 0, 0);
    }
    __syncthreads();   // compiler drains vmcnt before s_barrier

    // ---- compute: 48 MFMAs per wave ----
    const int fr = lane & 15;          // fragment row
    const int k8 = (lane >> 4) * 8;    // k-chunk
    bf16x8 af[4];
#pragma unroll
    for (int m = 0; m < 4; ++m)
      af[m] = *(const bf16x8*)&Ash[(wm + m * 16 + fr) * BKg + k8];
#pragma unroll
    for (int s = 0; s < 3; ++s) {
      bf16x8 bf[4];
#pragma unroll
      for (int n = 0; n < 4; ++n)
        bf[n] = *(const bf16x8*)&Bsh[s][(wn + n * 16 + fr) * BKg + k8];
#pragma unroll
      for (int m = 0; m < 4; ++m)
#pragma unroll
        for (int n = 0; n < 4; ++n)
          acc[m][n] = __builtin_amdgcn_mfma_f32_16x16x32_bf16(
              af[m], bf[n], acc[m][n], 0, 0, 0);
    }
  }

  // epilogue: C/D layout col=lane&15, row=(lane>>4)*4+j  [m89-verified]
  const int ccol = lane & 15;
  const int crow = (lane >> 4) * 4;
#pragma unroll
  for (int m = 0; m < 4; ++m)
#pragma unroll
    for (int n = 0; n < 4; ++n)
#pragma unroll
      for (int j = 0; j < 4; ++j) {
        int row = m0 + wm + m * 16 + crow + j;
        int col = n0 + wn + n * 16 + ccol;
        Cout[(size_t)row * N + col] = acc[m][n][j];
      }
}

// ---------------------------------------------------------------------------
// BN2 + LIF2 + residual (s1 from bf16 spikes, exact).  y:[T,B,C] in d_out.
// ---------------------------------------------------------------------------
__global__ __launch_bounds__(256) void bn_lif_add(
    const float* __restrict__ y, const __hip_bfloat16* __restrict__ s1b,
    const float* __restrict__ gam, const float* __restrict__ bet,
    const float* __restrict__ mu, const float* __restrict__ var,
    float* __restrict__ out) {
  int gid = blockIdx.x * blockDim.x + threadIdx.x;
  int o = gid & 1023;

  float inv = (float)((double)gam[o] / sqrt((double)var[o] + 1e-5));
  float add = (float)((double)bet[o] - (double)mu[o] * (double)inv);

  float v = 0.f;
  size_t base = (size_t)gid;  // (b*1024 + o), advance by BCEL per t
  for (int t = 0; t < T_; ++t) {
    size_t idx = base + (size_t)t * BCEL;
    float u = fmaf(y[idx], inv, add);
    v = fmaf(0.5f, v, u);
    bool sp = (v - 1.0f) >= 0.0f;
    float s1v = __bfloat162float(s1b[idx]);
    out[idx] = (sp ? 1.0f : 0.0f) + s1v;
    v = sp ? 0.0f : v;
  }
}

// ---------------------------------------------------------------------------
extern "C" void kernel_launch(void* const* d_in, const int* in_sizes, int n_in,
                              void* d_out, int out_size, void* d_ws,
                              size_t ws_size, hipStream_t stream) {
  const float* x     = (const float*)d_in[0];
  const float* pw_w  = (const float*)d_in[1];
  const float* pw_b  = (const float*)d_in[2];
  const float* dw_w  = (const float*)d_in[3];
  const float* dw_b  = (const float*)d_in[4];
  const float* bn1g  = (const float*)d_in[5];
  const float* bn1b  = (const float*)d_in[6];
  const float* bn1m  = (const float*)d_in[7];
  const float* bn1v  = (const float*)d_in[8];
  const float* lin_w = (const float*)d_in[9];
  const float* bn2g  = (const float*)d_in[10];
  const float* bn2b  = (const float*)d_in[11];
  const float* bn2m  = (const float*)d_in[12];
  const float* bn2v  = (const float*)d_in[13];
  float* out = (float*)d_out;                    // [T,B,C]

  // ws layout (max 52.4 MB, same as round 1):
  //   phase 1: p [B,T,C] f32 @ 0                       (52.4 MB)
  //   phase 2: Sb [T*B,C] bf16 @ 0                     (26.2 MB, over dead p)
  //            w0/w1/w2 bf16 @ 26.2/28.3/30.4 MB       (6.3 MB)
  float* p = (float*)d_ws;
  char* base = (char*)d_ws;
  __hip_bfloat16* Sb = (__hip_bfloat16*)base;
  const size_t SBB = (size_t)M_ * C_ * 2;        // 26,214,400
  const size_t WB  = (size_t)C_ * C_ * 2;        // 2,097,152
  __hip_bfloat16* w0 = (__hip_bfloat16*)(base + SBB);
  __hip_bfloat16* w1 = (__hip_bfloat16*)(base + SBB + WB);
  __hip_bfloat16* w2 = (__hip_bfloat16*)(base + SBB + 2 * WB);

  // 1) pointwise conv (f32 vector GEMM): p = x . pw_w^T + pw_b
  dim3 pw_grid(M_ / 64, C_ / 64);
  gemm_abt<<<pw_grid, 256, 0, stream>>>(x, pw_w, pw_b, p, M_, C_, CIN_);

  // 2) depthwise + BN1 + LIF1 -> s1 f32 in d_out [T,B,C]
  dw_bn_lif<<<BCEL / 256, 256, 0, stream>>>(p, dw_w, dw_b, bn1g, bn1b, bn1m,
                                            bn1v, out);

  // 3) spikes f32 -> bf16 (over dead p);  weights -> 3-way bf16 split
  cvt_bf16<<<(M_ * C_ / 8 + 255) / 256, 256, 0, stream>>>(out, Sb, M_ * C_);
  split_w<<<(C_ * C_ + 255) / 256, 256, 0, stream>>>(lin_w, w0, w1, w2, C_ * C_);

  // 4) MFMA GEMM: y = Sb . (w0+w1+w2)^T -> d_out (overwrites s1; Sb keeps it)
  gemm_mfma3<<<(M_ / BM) * (C_ / BN), 256, 0, stream>>>(Sb, w0, w1, w2, out);

  // 5) BN2 + LIF2 + residual (residual from Sb, exact), in place on d_out
  bn_lif_add<<<BCEL / 256, 256, 0, stream>>>(out, Sb, bn2g, bn2b, bn2m, bn2v,
                                             out);
}

// Round 3
// 212.144 us; speedup vs baseline: 2.1373x; 1.0923x over previous
//
#include <hip/hip_runtime.h>
#include <hip/hip_bf16.h>
#include <stdint.h>

// Problem constants
#define B_    64
#define T_    200
#define CIN_  80
#define C_    1024
#define M_    (B_ * T_)   // 12800
#define BCEL  (B_ * C_)   // 65536

typedef __attribute__((ext_vector_type(4))) float f32x4;
typedef __attribute__((ext_vector_type(8))) _Float16 f16x8;   // 8 f16 in 4 VGPRs
typedef __attribute__((ext_vector_type(4))) unsigned int u32x4;

// ---------------------------------------------------------------------------
// f32 GEMM (vector ALU) for the pointwise conv: C[M,N] = A[M,K]*B[N,K]^T + bias
// ---------------------------------------------------------------------------
__global__ __launch_bounds__(256) void gemm_abt(
    const float* __restrict__ A, const float* __restrict__ Bm,
    const float* __restrict__ bias, float* __restrict__ C,
    int M, int N, int K) {
  __shared__ float As[16][64];
  __shared__ float Bs[16][64];
  const int tid = threadIdx.x;
  const int tx = tid & 15;
  const int ty = tid >> 4;
  const int m0 = blockIdx.x * 64;
  const int n0 = blockIdx.y * 64;
  const int lr = tid >> 2;
  const int lc = (tid & 3) * 4;

  float acc[4][4] = {{0.f,0.f,0.f,0.f},{0.f,0.f,0.f,0.f},
                     {0.f,0.f,0.f,0.f},{0.f,0.f,0.f,0.f}};
  const float* Aro = A + (size_t)(m0 + lr) * K + lc;
  const float* Bro = Bm + (size_t)(n0 + lr) * K + lc;

  for (int k0 = 0; k0 < K; k0 += 16) {
    float4 a4 = *(const float4*)(Aro + k0);
    float4 b4 = *(const float4*)(Bro + k0);
    __syncthreads();
    As[lc + 0][lr] = a4.x; As[lc + 1][lr] = a4.y;
    As[lc + 2][lr] = a4.z; As[lc + 3][lr] = a4.w;
    Bs[lc + 0][lr] = b4.x; Bs[lc + 1][lr] = b4.y;
    Bs[lc + 2][lr] = b4.z; Bs[lc + 3][lr] = b4.w;
    __syncthreads();
#pragma unroll
    for (int kk = 0; kk < 16; ++kk) {
      float4 av = *(const float4*)&As[kk][ty * 4];
      float4 bv = *(const float4*)&Bs[kk][tx * 4];
      acc[0][0] = fmaf(av.x, bv.x, acc[0][0]);
      acc[0][1] = fmaf(av.x, bv.y, acc[0][1]);
      acc[0][2] = fmaf(av.x, bv.z, acc[0][2]);
      acc[0][3] = fmaf(av.x, bv.w, acc[0][3]);
      acc[1][0] = fmaf(av.y, bv.x, acc[1][0]);
      acc[1][1] = fmaf(av.y, bv.y, acc[1][1]);
      acc[1][2] = fmaf(av.y, bv.z, acc[1][2]);
      acc[1][3] = fmaf(av.y, bv.w, acc[1][3]);
      acc[2][0] = fmaf(av.z, bv.x, acc[2][0]);
      acc[2][1] = fmaf(av.z, bv.y, acc[2][1]);
      acc[2][2] = fmaf(av.z, bv.z, acc[2][2]);
      acc[2][3] = fmaf(av.z, bv.w, acc[2][3]);
      acc[3][0] = fmaf(av.w, bv.x, acc[3][0]);
      acc[3][1] = fmaf(av.w, bv.y, acc[3][1]);
      acc[3][2] = fmaf(av.w, bv.z, acc[3][2]);
      acc[3][3] = fmaf(av.w, bv.w, acc[3][3]);
    }
  }

  float bj[4] = {0.f, 0.f, 0.f, 0.f};
  if (bias) {
#pragma unroll
    for (int j = 0; j < 4; ++j) bj[j] = bias[n0 + tx * 4 + j];
  }
#pragma unroll
  for (int i = 0; i < 4; ++i) {
    int m = m0 + ty * 4 + i;
    float4 o4;
    o4.x = acc[i][0] + bj[0];
    o4.y = acc[i][1] + bj[1];
    o4.z = acc[i][2] + bj[2];
    o4.w = acc[i][3] + bj[3];
    *(float4*)&C[(size_t)m * N + n0 + tx * 4] = o4;
  }
}

// ---------------------------------------------------------------------------
// Depthwise conv (K=7, same pad) + BN1 + LIF1 scan.
// p:[B,T,C] f32 -> spikes as f16 bits (0x3C00 / 0) in s1:[T,B,C]
// ---------------------------------------------------------------------------
__global__ __launch_bounds__(256) void dw_bn_lif(
    const float* __restrict__ p, const float* __restrict__ dw_w,
    const float* __restrict__ dw_b, const float* __restrict__ gam,
    const float* __restrict__ bet, const float* __restrict__ mu,
    const float* __restrict__ var, ushort* __restrict__ s1) {
  int gid = blockIdx.x * blockDim.x + threadIdx.x;
  int b = gid >> 10;
  int o = gid & 1023;

  float w[7];
#pragma unroll
  for (int k = 0; k < 7; ++k) w[k] = dw_w[o * 7 + k];
  float db = dw_b[o];
  float inv = (float)((double)gam[o] / sqrt((double)var[o] + 1e-5));
  float add = (float)((double)bet[o] - (double)mu[o] * (double)inv);

  const float* pp = p + (size_t)b * T_ * C_ + o;
  float r[7];
  r[0] = 0.f; r[1] = 0.f; r[2] = 0.f;
#pragma unroll
  for (int i = 0; i < 4; ++i) r[3 + i] = pp[(size_t)i * C_];

  float v = 0.f;
  size_t obase = (size_t)b * C_ + o;
  for (int t = 0; t < T_; ++t) {
    float u = db;
#pragma unroll
    for (int k = 0; k < 7; ++k) u = fmaf(w[k], r[k], u);
    u = fmaf(u, inv, add);
    v = fmaf(0.5f, v, u);
    bool sp = (v - 1.0f) >= 0.0f;
    s1[obase + (size_t)t * BCEL] = sp ? (ushort)0x3C00 : (ushort)0;
    v = sp ? 0.0f : v;
#pragma unroll
    for (int k = 0; k < 6; ++k) r[k] = r[k + 1];
    int tn = t + 4;
    r[6] = (tn < T_) ? pp[(size_t)tn * C_] : 0.f;
  }
}

// ---------------------------------------------------------------------------
// Scaled 2-way f16 split: w ~= w0 + 2^-11 * w1s, residual <= 2^-22 |w|.
// w0 forced to 0 in the f16-subnormal range so MFMA denorm-flush can't bite.
// ---------------------------------------------------------------------------
__global__ __launch_bounds__(256) void split_w(
    const float* __restrict__ w, ushort* __restrict__ w0,
    ushort* __restrict__ w1, int n) {
  int i = blockIdx.x * 256 + threadIdx.x;
  if (i >= n) return;
  float x = w[i];
  union { _Float16 h; ushort u; } h0, h1;
  h0.h = (_Float16)x;
  if (fabsf(x) < 6.1035156e-5f) h0.u = 0;   // keep w0 out of f16 subnormals
  float r = x - (float)h0.h;
  h1.h = (_Float16)(r * 2048.0f);           // 2^11, w1s in normal f16 range
  w0[i] = h0.u;
  w1[i] = h1.u;
}

// ---------------------------------------------------------------------------
// MFMA f16 GEMM with 2-term weight split, single accumulator:
//   y = S*w0^T + (S&0x1000)*w1s^T       (S&0x1000 == S * 2^-11 exactly)
// 128x128 tile, BK=32, 4 waves (2x2), global_load_lds width-16 staging.
// ---------------------------------------------------------------------------
#define BM 128
#define BN 128
#define BKg 32

__global__ __launch_bounds__(256) void gemm_mfma2(
    const ushort* __restrict__ A,
    const ushort* __restrict__ B0,
    const ushort* __restrict__ B1,
    float* __restrict__ Cout) {
  const int K = C_;
  const int N = C_;
  __shared__ __align__(16) ushort Ash[BM * BKg];      // 8 KB
  __shared__ __align__(16) ushort Bsh[2][BN * BKg];   // 16 KB

  const int tid  = threadIdx.x;
  const int lane = tid & 63;
  const int wm = ((tid >> 6) >> 1) * 64;
  const int wn = ((tid >> 6) & 1) * 64;

  // XCD-aware swizzle: 800 blocks -> 100 contiguous per XCD, n fastest
  int lin = blockIdx.x;
  int qq = gridDim.x >> 3;                 // 100
  int wg = (lin & 7) * qq + (lin >> 3);
  const int m0 = (wg >> 3) * BM;
  const int n0 = (wg & 7) * BN;

  const int r0 = tid >> 2, kc0 = (tid & 3) * 8;
  const int r1 = (tid + 256) >> 2, kc1 = ((tid + 256) & 3) * 8;

  f32x4 acc[4][4] = {};

  for (int k0 = 0; k0 < K; k0 += BKg) {
    __syncthreads();
    // ---- stage A tile (f16 spikes) ----
    {
      const ushort* s0 = A + (size_t)(m0 + r0) * K + k0 + kc0;
      const ushort* s1p = A + (size_t)(m0 + r1) * K + k0 + kc1;
      __builtin_amdgcn_global_load_lds(
          (const __attribute__((address_space(1))) uint32_t*)s0,
          (__attribute__((address_space(3))) uint32_t*)&Ash[tid * 8], 16, 0, 0);
      __builtin_amdgcn_global_load_lds(
          (const __attribute__((address_space(1))) uint32_t*)s1p,
          (__attribute__((address_space(3))) uint32_t*)&Ash[(tid + 256) * 8], 16, 0, 0);
    }
    // ---- stage 2 B tiles ----
#pragma unroll
    for (int s = 0; s < 2; ++s) {
      const ushort* Bp = (s == 0) ? B0 : B1;
      const ushort* s0 = Bp + (size_t)(n0 + r0) * K + k0 + kc0;
      const ushort* s1p = Bp + (size_t)(n0 + r1) * K + k0 + kc1;
      __builtin_amdgcn_global_load_lds(
          (const __attribute__((address_space(1))) uint32_t*)s0,
          (__attribute__((address_space(3))) uint32_t*)&Bsh[s][tid * 8], 16, 0, 0);
      __builtin_amdgcn_global_load_lds(
          (const __attribute__((address_space(1))) uint32_t*)s1p,
          (__attribute__((address_space(3))) uint32_t*)&Bsh[s][(tid + 256) * 8], 16, 0, 0);
    }
    __syncthreads();   // compiler drains vmcnt before s_barrier

    // ---- compute: 32 MFMAs + 16 v_and per wave ----
    const int fr = lane & 15;
    const int k8 = (lane >> 4) * 8;
    union HU { f16x8 h; u32x4 u; };
    f16x8 af[4], a2f[4];
#pragma unroll
    for (int m = 0; m < 4; ++m) {
      HU t;
      t.h = *(const f16x8*)&Ash[(wm + m * 16 + fr) * BKg + k8];
      af[m] = t.h;
      t.u &= 0x10001000u;      // {0,1.0f16} -> {0, 2^-11} exactly
      a2f[m] = t.h;
    }
    f16x8 b0f[4], b1f[4];
#pragma unroll
    for (int n = 0; n < 4; ++n) {
      b0f[n] = *(const f16x8*)&Bsh[0][(wn + n * 16 + fr) * BKg + k8];
      b1f[n] = *(const f16x8*)&Bsh[1][(wn + n * 16 + fr) * BKg + k8];
    }
#pragma unroll
    for (int m = 0; m < 4; ++m)
#pragma unroll
      for (int n = 0; n < 4; ++n) {
        acc[m][n] = __builtin_amdgcn_mfma_f32_16x16x32_f16(
            af[m], b0f[n], acc[m][n], 0, 0, 0);
        acc[m][n] = __builtin_amdgcn_mfma_f32_16x16x32_f16(
            a2f[m], b1f[n], acc[m][n], 0, 0, 0);
      }
  }

  // epilogue: C/D layout col=lane&15, row=(lane>>4)*4+j
  const int ccol = lane & 15;
  const int crow = (lane >> 4) * 4;
#pragma unroll
  for (int m = 0; m < 4; ++m)
#pragma unroll
    for (int n = 0; n < 4; ++n)
#pragma unroll
      for (int j = 0; j < 4; ++j) {
        int row = m0 + wm + m * 16 + crow + j;
        int col = n0 + wn + n * 16 + ccol;
        Cout[(size_t)row * N + col] = acc[m][n][j];
      }
}

// ---------------------------------------------------------------------------
// BN2 + LIF2 + residual (s1 from f16 spike bits, exact). In-place on d_out.
// ---------------------------------------------------------------------------
__global__ __launch_bounds__(256) void bn_lif_add(
    const float* __restrict__ y, const ushort* __restrict__ s1b,
    const float* __restrict__ gam, const float* __restrict__ bet,
    const float* __restrict__ mu, const float* __restrict__ var,
    float* __restrict__ out) {
  int gid = blockIdx.x * blockDim.x + threadIdx.x;
  int o = gid & 1023;

  float inv = (float)((double)gam[o] / sqrt((double)var[o] + 1e-5));
  float add = (float)((double)bet[o] - (double)mu[o] * (double)inv);

  float v = 0.f;
  size_t base = (size_t)gid;
  for (int t = 0; t < T_; ++t) {
    size_t idx = base + (size_t)t * BCEL;
    float u = fmaf(y[idx], inv, add);
    v = fmaf(0.5f, v, u);
    bool sp = (v - 1.0f) >= 0.0f;
    float s1v = s1b[idx] ? 1.0f : 0.0f;
    out[idx] = (sp ? 1.0f : 0.0f) + s1v;
    v = sp ? 0.0f : v;
  }
}

// ---------------------------------------------------------------------------
extern "C" void kernel_launch(void* const* d_in, const int* in_sizes, int n_in,
                              void* d_out, int out_size, void* d_ws,
                              size_t ws_size, hipStream_t stream) {
  const float* x     = (const float*)d_in[0];
  const float* pw_w  = (const float*)d_in[1];
  const float* pw_b  = (const float*)d_in[2];
  const float* dw_w  = (const float*)d_in[3];
  const float* dw_b  = (const float*)d_in[4];
  const float* bn1g  = (const float*)d_in[5];
  const float* bn1b  = (const float*)d_in[6];
  const float* bn1m  = (const float*)d_in[7];
  const float* bn1v  = (const float*)d_in[8];
  const float* lin_w = (const float*)d_in[9];
  const float* bn2g  = (const float*)d_in[10];
  const float* bn2b  = (const float*)d_in[11];
  const float* bn2m  = (const float*)d_in[12];
  const float* bn2v  = (const float*)d_in[13];

  // ws layout (max extent 52.4 MB, proven available):
  //   phase 1: p [B,T,C] f32 @ 0                        (52.4 MB)
  //   phase 2: Sb f16 @ 0 (26.2, memcpy'd from d_out)
  //            w0 @ 26.2MB, w1s @ 28.3MB (2 MB each)
  // d_out: spikes f16 @ 0 (26.2) -> y f32 (52.4) -> final out (in place)
  float* p = (float*)d_ws;
  char* wsb = (char*)d_ws;
  const size_t SBB = (size_t)M_ * C_ * 2;        // 26,214,400
  const size_t WB  = (size_t)C_ * C_ * 2;        // 2,097,152
  ushort* Sb  = (ushort*)wsb;
  ushort* w0  = (ushort*)(wsb + SBB);
  ushort* w1s = (ushort*)(wsb + SBB + WB);
  ushort* Sout = (ushort*)d_out;                 // spikes staged in d_out first
  float* out = (float*)d_out;

  // 1) pointwise conv (f32 vector GEMM): p = x . pw_w^T + pw_b
  dim3 pw_grid(M_ / 64, C_ / 64);
  gemm_abt<<<pw_grid, 256, 0, stream>>>(x, pw_w, pw_b, p, M_, C_, CIN_);

  // 2) depthwise + BN1 + LIF1 -> f16 spikes in d_out [T,B,C]
  dw_bn_lif<<<BCEL / 256, 256, 0, stream>>>(p, dw_w, dw_b, bn1g, bn1b, bn1m,
                                            bn1v, Sout);

  // 3) weight split (p is dead now); spike copy d_out -> ws
  split_w<<<(C_ * C_ + 255) / 256, 256, 0, stream>>>(lin_w, w0, w1s, C_ * C_);
  hipMemcpyAsync(Sb, Sout, SBB, hipMemcpyDeviceToDevice, stream);

  // 4) MFMA GEMM: y = Sb.(w0 + 2^-11 w1s)^T -> d_out (overwrites spike copy)
  gemm_mfma2<<<(M_ / BM) * (C_ / BN), 256, 0, stream>>>(Sb, w0, w1s, out);

  // 5) BN2 + LIF2 + residual, same-index in-place on d_out
  bn_lif_add<<<BCEL / 256, 256, 0, stream>>>(out, Sb, bn2g, bn2b, bn2m, bn2v,
                                             out);
}

// Round 5
// 159.993 us; speedup vs baseline: 2.8339x; 1.3260x over previous
//
#include <hip/hip_runtime.h>
#include <hip/hip_bf16.h>
#include <stdint.h>

// Problem constants
#define B_    64
#define T_    200
#define CIN_  80
#define C_    1024
#define M_    (B_ * T_)   // 12800
#define BCEL  (B_ * C_)   // 65536

typedef __attribute__((ext_vector_type(4))) float f32x4;
typedef __attribute__((ext_vector_type(8))) _Float16 f16x8;   // 8 f16 in 4 VGPRs
typedef __attribute__((ext_vector_type(4))) unsigned int u32x4;

// ---------------------------------------------------------------------------
// f32 GEMM (vector ALU) for the pointwise conv: C[M,N] = A[M,K]*B[N,K]^T + bias
// NOTE: per-output FMA chain is strict ascending-k — bit-identical to the
// rounds-1..3 kernel that validated absmax 0.0. Do not change the arithmetic.
// ---------------------------------------------------------------------------
__global__ __launch_bounds__(256) void gemm_abt(
    const float* __restrict__ A, const float* __restrict__ Bm,
    const float* __restrict__ bias, float* __restrict__ C,
    int M, int N, int K) {
  __shared__ float As[16][64];
  __shared__ float Bs[16][64];
  const int tid = threadIdx.x;
  const int tx = tid & 15;
  const int ty = tid >> 4;
  const int m0 = blockIdx.x * 64;
  const int n0 = blockIdx.y * 64;
  const int lr = tid >> 2;
  const int lc = (tid & 3) * 4;

  float acc[4][4] = {{0.f,0.f,0.f,0.f},{0.f,0.f,0.f,0.f},
                     {0.f,0.f,0.f,0.f},{0.f,0.f,0.f,0.f}};
  const float* Aro = A + (size_t)(m0 + lr) * K + lc;
  const float* Bro = Bm + (size_t)(n0 + lr) * K + lc;

  for (int k0 = 0; k0 < K; k0 += 16) {
    float4 a4 = *(const float4*)(Aro + k0);
    float4 b4 = *(const float4*)(Bro + k0);
    __syncthreads();
    As[lc + 0][lr] = a4.x; As[lc + 1][lr] = a4.y;
    As[lc + 2][lr] = a4.z; As[lc + 3][lr] = a4.w;
    Bs[lc + 0][lr] = b4.x; Bs[lc + 1][lr] = b4.y;
    Bs[lc + 2][lr] = b4.z; Bs[lc + 3][lr] = b4.w;
    __syncthreads();
#pragma unroll
    for (int kk = 0; kk < 16; ++kk) {
      float4 av = *(const float4*)&As[kk][ty * 4];
      float4 bv = *(const float4*)&Bs[kk][tx * 4];
      acc[0][0] = fmaf(av.x, bv.x, acc[0][0]);
      acc[0][1] = fmaf(av.x, bv.y, acc[0][1]);
      acc[0][2] = fmaf(av.x, bv.z, acc[0][2]);
      acc[0][3] = fmaf(av.x, bv.w, acc[0][3]);
      acc[1][0] = fmaf(av.y, bv.x, acc[1][0]);
      acc[1][1] = fmaf(av.y, bv.y, acc[1][1]);
      acc[1][2] = fmaf(av.y, bv.z, acc[1][2]);
      acc[1][3] = fmaf(av.y, bv.w, acc[1][3]);
      acc[2][0] = fmaf(av.z, bv.x, acc[2][0]);
      acc[2][1] = fmaf(av.z, bv.y, acc[2][1]);
      acc[2][2] = fmaf(av.z, bv.z, acc[2][2]);
      acc[2][3] = fmaf(av.z, bv.w, acc[2][3]);
      acc[3][0] = fmaf(av.w, bv.x, acc[3][0]);
      acc[3][1] = fmaf(av.w, bv.y, acc[3][1]);
      acc[3][2] = fmaf(av.w, bv.z, acc[3][2]);
      acc[3][3] = fmaf(av.w, bv.w, acc[3][3]);
    }
  }

  float bj[4] = {0.f, 0.f, 0.f, 0.f};
  if (bias) {
#pragma unroll
    for (int j = 0; j < 4; ++j) bj[j] = bias[n0 + tx * 4 + j];
  }
#pragma unroll
  for (int i = 0; i < 4; ++i) {
    int m = m0 + ty * 4 + i;
    float4 o4;
    o4.x = acc[i][0] + bj[0];
    o4.y = acc[i][1] + bj[1];
    o4.z = acc[i][2] + bj[2];
    o4.w = acc[i][3] + bj[3];
    *(float4*)&C[(size_t)m * N + n0 + tx * 4] = o4;
  }
}

// ---------------------------------------------------------------------------
// Depthwise conv (K=7, same pad) + BN1 + LIF1 scan, chunked T by 8 with
// 8-deep load prefetch (latency hiding at the fixed 1-wave/SIMD occupancy).
// Arithmetic per step is bit-identical to the round-3 version.
// p:[B,T,C] f32 -> spikes as f16 bits (0x3C00 / 0) in s1:[T,B,C]
// ---------------------------------------------------------------------------
__global__ __launch_bounds__(256) void dw_bn_lif(
    const float* __restrict__ p, const float* __restrict__ dw_w,
    const float* __restrict__ dw_b, const float* __restrict__ gam,
    const float* __restrict__ bet, const float* __restrict__ mu,
    const float* __restrict__ var, ushort* __restrict__ s1) {
  int gid = blockIdx.x * blockDim.x + threadIdx.x;
  int b = gid >> 10;
  int o = gid & 1023;

  float w[7];
#pragma unroll
  for (int k = 0; k < 7; ++k) w[k] = dw_w[o * 7 + k];
  float db = dw_b[o];
  float inv = (float)((double)gam[o] / sqrt((double)var[o] + 1e-5));
  float add = (float)((double)bet[o] - (double)mu[o] * (double)inv);

  const float* pp = p + (size_t)b * T_ * C_ + o;
  // win[i] = p[t0 - 3 + i]; covers the 7 taps for 8 consecutive steps
  float win[14];
  win[0] = 0.f; win[1] = 0.f; win[2] = 0.f;
#pragma unroll
  for (int i = 0; i < 11; ++i) win[3 + i] = pp[(size_t)i * C_];

  float v = 0.f;
  size_t obase = (size_t)b * C_ + o;
  for (int c = 0; c < T_ / 8; ++c) {
    int t0 = c * 8;
    // prefetch next chunk's inputs: p[t0+11 .. t0+18]
    float nx[8];
#pragma unroll
    for (int j = 0; j < 8; ++j) {
      int tn = t0 + 11 + j;
      nx[j] = (tn < T_) ? pp[(size_t)tn * C_] : 0.f;
    }
#pragma unroll
    for (int s = 0; s < 8; ++s) {
      float u = db;
#pragma unroll
      for (int k = 0; k < 7; ++k) u = fmaf(w[k], win[s + k], u);
      u = fmaf(u, inv, add);
      v = fmaf(0.5f, v, u);
      bool sp = (v - 1.0f) >= 0.0f;
      s1[obase + (size_t)(t0 + s) * BCEL] = sp ? (ushort)0x3C00 : (ushort)0;
      v = sp ? 0.0f : v;
    }
#pragma unroll
    for (int i = 0; i < 6; ++i) win[i] = win[i + 8];
#pragma unroll
    for (int j = 0; j < 8; ++j) win[6 + j] = nx[j];
  }
}

// ---------------------------------------------------------------------------
// Scaled 2-way f16 split of the linear weights: w ~= w0 + 2^-11 w1s.
// Exact when multiplied by {0,1} spikes (products exact, f32 accum).
// ---------------------------------------------------------------------------
__global__ __launch_bounds__(256) void split_w(
    const float* __restrict__ w, ushort* __restrict__ w0,
    ushort* __restrict__ w1, int n) {
  int i = blockIdx.x * 256 + threadIdx.x;
  if (i >= n) return;
  float x = w[i];
  union { _Float16 h; ushort u; } h0, h1;
  h0.h = (_Float16)x;
  if (fabsf(x) < 6.1035156e-5f) h0.u = 0;   // keep w0 out of f16 subnormals
  float r = x - (float)h0.h;
  h1.h = (_Float16)(r * 2048.0f);
  w0[i] = h0.u;
  w1[i] = h1.u;
}

// ---------------------------------------------------------------------------
// MFMA f16 GEMM with 2-term weight split, single accumulator:
//   y = S*w0^T + (S&0x1000)*w1s^T       (S&0x1000 == S * 2^-11 exactly)
// 128x128 tile, BK=32, 4 waves (2x2), global_load_lds width-16 staging.
// ---------------------------------------------------------------------------
#define BM 128
#define BN 128
#define BKg 32

__global__ __launch_bounds__(256) void gemm_mfma2(
    const ushort* __restrict__ A,
    const ushort* __restrict__ B0,
    const ushort* __restrict__ B1,
    float* __restrict__ Cout) {
  const int K = C_;
  const int N = C_;
  __shared__ __align__(16) ushort Ash[BM * BKg];      // 8 KB
  __shared__ __align__(16) ushort Bsh[2][BN * BKg];   // 16 KB

  const int tid  = threadIdx.x;
  const int lane = tid & 63;
  const int wm = ((tid >> 6) >> 1) * 64;
  const int wn = ((tid >> 6) & 1) * 64;

  // XCD-aware swizzle: 800 blocks -> 100 contiguous per XCD, n fastest
  int lin = blockIdx.x;
  int qq = gridDim.x >> 3;                 // 100
  int wg = (lin & 7) * qq + (lin >> 3);
  const int m0 = (wg >> 3) * BM;
  const int n0 = (wg & 7) * BN;

  const int r0 = tid >> 2, kc0 = (tid & 3) * 8;
  const int r1 = (tid + 256) >> 2, kc1 = ((tid + 256) & 3) * 8;

  f32x4 acc[4][4] = {};

  for (int k0 = 0; k0 < K; k0 += BKg) {
    __syncthreads();
    {
      const ushort* s0 = A + (size_t)(m0 + r0) * K + k0 + kc0;
      const ushort* s1p = A + (size_t)(m0 + r1) * K + k0 + kc1;
      __builtin_amdgcn_global_load_lds(
          (const __attribute__((address_space(1))) uint32_t*)s0,
          (__attribute__((address_space(3))) uint32_t*)&Ash[tid * 8], 16, 0, 0);
      __builtin_amdgcn_global_load_lds(
          (const __attribute__((address_space(1))) uint32_t*)s1p,
          (__attribute__((address_space(3))) uint32_t*)&Ash[(tid + 256) * 8], 16, 0, 0);
    }
#pragma unroll
    for (int s = 0; s < 2; ++s) {
      const ushort* Bp = (s == 0) ? B0 : B1;
      const ushort* s0 = Bp + (size_t)(n0 + r0) * K + k0 + kc0;
      const ushort* s1p = Bp + (size_t)(n0 + r1) * K + k0 + kc1;
      __builtin_amdgcn_global_load_lds(
          (const __attribute__((address_space(1))) uint32_t*)s0,
          (__attribute__((address_space(3))) uint32_t*)&Bsh[s][tid * 8], 16, 0, 0);
      __builtin_amdgcn_global_load_lds(
          (const __attribute__((address_space(1))) uint32_t*)s1p,
          (__attribute__((address_space(3))) uint32_t*)&Bsh[s][(tid + 256) * 8], 16, 0, 0);
    }
    __syncthreads();

    const int fr = lane & 15;
    const int k8 = (lane >> 4) * 8;
    union HU { f16x8 h; u32x4 u; };
    f16x8 af[4], a2f[4];
#pragma unroll
    for (int m = 0; m < 4; ++m) {
      HU t;
      t.h = *(const f16x8*)&Ash[(wm + m * 16 + fr) * BKg + k8];
      af[m] = t.h;
      t.u &= 0x10001000u;      // {0,1.0f16} -> {0, 2^-11} exactly
      a2f[m] = t.h;
    }
    f16x8 b0f[4], b1f[4];
#pragma unroll
    for (int n = 0; n < 4; ++n) {
      b0f[n] = *(const f16x8*)&Bsh[0][(wn + n * 16 + fr) * BKg + k8];
      b1f[n] = *(const f16x8*)&Bsh[1][(wn + n * 16 + fr) * BKg + k8];
    }
#pragma unroll
    for (int m = 0; m < 4; ++m)
#pragma unroll
      for (int n = 0; n < 4; ++n) {
        acc[m][n] = __builtin_amdgcn_mfma_f32_16x16x32_f16(
            af[m], b0f[n], acc[m][n], 0, 0, 0);
        acc[m][n] = __builtin_amdgcn_mfma_f32_16x16x32_f16(
            a2f[m], b1f[n], acc[m][n], 0, 0, 0);
      }
  }

  const int ccol = lane & 15;
  const int crow = (lane >> 4) * 4;
#pragma unroll
  for (int m = 0; m < 4; ++m)
#pragma unroll
    for (int n = 0; n < 4; ++n)
#pragma unroll
      for (int j = 0; j < 4; ++j) {
        int row = m0 + wm + m * 16 + crow + j;
        int col = n0 + wn + n * 16 + ccol;
        Cout[(size_t)row * N + col] = acc[m][n][j];
      }
}

// ---------------------------------------------------------------------------
// BN2 + LIF2 + residual, chunked T by 8 with next-chunk prefetch.
// y:[T,B,C] f32; s1b: f16 spike bits; out:[T,B,C] f32. Safe when y == out
// (each element read+written only by its owner thread, read first).
// ---------------------------------------------------------------------------
__global__ __launch_bounds__(256) void bn_lif_add(
    const float* __restrict__ y, const ushort* __restrict__ s1b,
    const float* __restrict__ gam, const float* __restrict__ bet,
    const float* __restrict__ mu, const float* __restrict__ var,
    float* __restrict__ out) {
  int gid = blockIdx.x * blockDim.x + threadIdx.x;
  int o = gid & 1023;

  float inv = (float)((double)gam[o] / sqrt((double)var[o] + 1e-5));
  float add = (float)((double)bet[o] - (double)mu[o] * (double)inv);

  float v = 0.f;
  size_t base = (size_t)gid;
  float yv[8]; ushort sv[8];
#pragma unroll
  for (int j = 0; j < 8; ++j) {
    yv[j] = y[base + (size_t)j * BCEL];
    sv[j] = s1b[base + (size_t)j * BCEL];
  }
  for (int c = 0; c < T_ / 8; ++c) {
    int t0 = c * 8;
    float yn[8] = {0,0,0,0,0,0,0,0}; ushort sn[8] = {0,0,0,0,0,0,0,0};
    if (c + 1 < T_ / 8) {
#pragma unroll
      for (int j = 0; j < 8; ++j) {
        size_t idx = base + (size_t)(t0 + 8 + j) * BCEL;
        yn[j] = y[idx];
        sn[j] = s1b[idx];
      }
    }
#pragma unroll
    for (int j = 0; j < 8; ++j) {
      float u = fmaf(yv[j], inv, add);
      v = fmaf(0.5f, v, u);
      bool sp = (v - 1.0f) >= 0.0f;
      float s1v = sv[j] ? 1.0f : 0.0f;
      out[base + (size_t)(t0 + j) * BCEL] = (sp ? 1.0f : 0.0f) + s1v;
      v = sp ? 0.0f : v;
    }
#pragma unroll
    for (int j = 0; j < 8; ++j) { yv[j] = yn[j]; sv[j] = sn[j]; }
  }
}

// ---------------------------------------------------------------------------
extern "C" void kernel_launch(void* const* d_in, const int* in_sizes, int n_in,
                              void* d_out, int out_size, void* d_ws,
                              size_t ws_size, hipStream_t stream) {
  const float* x     = (const float*)d_in[0];
  const float* pw_w  = (const float*)d_in[1];
  const float* pw_b  = (const float*)d_in[2];
  const float* dw_w  = (const float*)d_in[3];
  const float* dw_b  = (const float*)d_in[4];
  const float* bn1g  = (const float*)d_in[5];
  const float* bn1b  = (const float*)d_in[6];
  const float* bn1m  = (const float*)d_in[7];
  const float* bn1v  = (const float*)d_in[8];
  const float* lin_w = (const float*)d_in[9];
  const float* bn2g  = (const float*)d_in[10];
  const float* bn2b  = (const float*)d_in[11];
  const float* bn2m  = (const float*)d_in[12];
  const float* bn2v  = (const float*)d_in[13];

  char* wsb  = (char*)d_ws;
  char* outb = (char*)d_out;
  const size_t PB  = (size_t)M_ * C_ * 4;        // 52,428,800  (p / y, f32)
  const size_t SBB = (size_t)M_ * C_ * 2;        // 26,214,400  (spikes, f16)
  const size_t WB  = (size_t)C_ * C_ * 2;        //  2,097,152  (lin_w term)

  float* p = (float*)d_ws;                       // [B,T,C] f32

  const bool primary = ws_size >= PB + SBB;
  // primary : spikes @ ws+PB, lin-weights @ d_out[0:4MB), y @ ws[0:PB)
  // fallback: spikes @ d_out, memcpy -> ws[0:SBB), weights @ ws+SBB, y @ d_out
  ushort* spikes = primary ? (ushort*)(wsb + PB) : (ushort*)d_out;
  ushort* w0  = primary ? (ushort*)outb : (ushort*)(wsb + SBB);
  ushort* w1s = w0 + (size_t)C_ * C_;
  ushort* Sgemm = primary ? spikes : (ushort*)d_ws;
  float* ybuf = primary ? (float*)d_ws : (float*)d_out;

  // 1) pointwise conv (f32 vector GEMM, exact): p = x . pw_w^T + pw_b
  dim3 pw_grid(M_ / 64, C_ / 64);
  gemm_abt<<<pw_grid, 256, 0, stream>>>(x, pw_w, pw_b, p, M_, C_, CIN_);

  // 2) depthwise + BN1 + LIF1 -> f16 spike bits [T,B,C]
  dw_bn_lif<<<BCEL / 256, 256, 0, stream>>>(p, dw_w, dw_b, bn1g, bn1b, bn1m,
                                            bn1v, spikes);

  // 3) fallback only: move spikes out of d_out before GEMM overwrites it
  if (!primary)
    hipMemcpyAsync(d_ws, d_out, SBB, hipMemcpyDeviceToDevice, stream);

  // 4) linear weight split
  split_w<<<(C_ * C_ + 255) / 256, 256, 0, stream>>>(lin_w, w0, w1s, C_ * C_);

  // 5) linear MFMA GEMM: y = S.(w0 + 2^-11 w1s)^T
  gemm_mfma2<<<(M_ / BM) * (C_ / BN), 256, 0, stream>>>(Sgemm, w0, w1s, ybuf);

  // 6) BN2 + LIF2 + residual -> d_out
  bn_lif_add<<<BCEL / 256, 256, 0, stream>>>(ybuf, Sgemm, bn2g, bn2b, bn2m,
                                             bn2v, (float*)d_out);
}

// Round 6
// 153.277 us; speedup vs baseline: 2.9581x; 1.0438x over previous
//
#include <hip/hip_runtime.h>
#include <hip/hip_bf16.h>
#include <stdint.h>

// Problem constants
#define B_    64
#define T_    200
#define CIN_  80
#define C_    1024
#define M_    (B_ * T_)   // 12800
#define BCEL  (B_ * C_)   // 65536

typedef __attribute__((ext_vector_type(4))) float f32x4;
typedef __attribute__((ext_vector_type(8))) _Float16 f16x8;   // 8 f16 in 4 VGPRs
typedef __attribute__((ext_vector_type(4))) unsigned int u32x4;

// ---------------------------------------------------------------------------
// f32 GEMM (vector ALU) for the pointwise conv: C[M,N] = A[M,K]*B[N,K]^T + bias
// Per-output FMA chain is strict ascending-k — bit-identical to the validated
// rounds-1..5 kernel. Only LOAD SCHEDULING changed (next-chunk reg prefetch).
// ---------------------------------------------------------------------------
__global__ __launch_bounds__(256) void gemm_abt(
    const float* __restrict__ A, const float* __restrict__ Bm,
    const float* __restrict__ bias, float* __restrict__ C,
    int M, int N, int K) {
  __shared__ float As[16][64];
  __shared__ float Bs[16][64];
  const int tid = threadIdx.x;
  const int tx = tid & 15;
  const int ty = tid >> 4;
  const int m0 = blockIdx.x * 64;
  const int n0 = blockIdx.y * 64;
  const int lr = tid >> 2;
  const int lc = (tid & 3) * 4;

  float acc[4][4] = {{0.f,0.f,0.f,0.f},{0.f,0.f,0.f,0.f},
                     {0.f,0.f,0.f,0.f},{0.f,0.f,0.f,0.f}};
  const float* Aro = A + (size_t)(m0 + lr) * K + lc;
  const float* Bro = Bm + (size_t)(n0 + lr) * K + lc;

  // prefetch k0 = 0
  float4 a4 = *(const float4*)(Aro);
  float4 b4 = *(const float4*)(Bro);

  for (int k0 = 0; k0 < K; k0 += 16) {
    __syncthreads();
    As[lc + 0][lr] = a4.x; As[lc + 1][lr] = a4.y;
    As[lc + 2][lr] = a4.z; As[lc + 3][lr] = a4.w;
    Bs[lc + 0][lr] = b4.x; Bs[lc + 1][lr] = b4.y;
    Bs[lc + 2][lr] = b4.z; Bs[lc + 3][lr] = b4.w;
    __syncthreads();
    if (k0 + 16 < K) {           // prefetch next chunk; overlaps FMA block
      a4 = *(const float4*)(Aro + k0 + 16);
      b4 = *(const float4*)(Bro + k0 + 16);
    }
#pragma unroll
    for (int kk = 0; kk < 16; ++kk) {
      float4 av = *(const float4*)&As[kk][ty * 4];
      float4 bv = *(const float4*)&Bs[kk][tx * 4];
      acc[0][0] = fmaf(av.x, bv.x, acc[0][0]);
      acc[0][1] = fmaf(av.x, bv.y, acc[0][1]);
      acc[0][2] = fmaf(av.x, bv.z, acc[0][2]);
      acc[0][3] = fmaf(av.x, bv.w, acc[0][3]);
      acc[1][0] = fmaf(av.y, bv.x, acc[1][0]);
      acc[1][1] = fmaf(av.y, bv.y, acc[1][1]);
      acc[1][2] = fmaf(av.y, bv.z, acc[1][2]);
      acc[1][3] = fmaf(av.y, bv.w, acc[1][3]);
      acc[2][0] = fmaf(av.z, bv.x, acc[2][0]);
      acc[2][1] = fmaf(av.z, bv.y, acc[2][1]);
      acc[2][2] = fmaf(av.z, bv.z, acc[2][2]);
      acc[2][3] = fmaf(av.z, bv.w, acc[2][3]);
      acc[3][0] = fmaf(av.w, bv.x, acc[3][0]);
      acc[3][1] = fmaf(av.w, bv.y, acc[3][1]);
      acc[3][2] = fmaf(av.w, bv.z, acc[3][2]);
      acc[3][3] = fmaf(av.w, bv.w, acc[3][3]);
    }
  }

  float bj[4] = {0.f, 0.f, 0.f, 0.f};
  if (bias) {
#pragma unroll
    for (int j = 0; j < 4; ++j) bj[j] = bias[n0 + tx * 4 + j];
  }
#pragma unroll
  for (int i = 0; i < 4; ++i) {
    int m = m0 + ty * 4 + i;
    float4 o4;
    o4.x = acc[i][0] + bj[0];
    o4.y = acc[i][1] + bj[1];
    o4.z = acc[i][2] + bj[2];
    o4.w = acc[i][3] + bj[3];
    *(float4*)&C[(size_t)m * N + n0 + tx * 4] = o4;
  }
}

// ---------------------------------------------------------------------------
// Depthwise conv (K=7, same pad) + BN1 + LIF1 scan, chunked T by 8 with
// 8-deep load prefetch. p:[B,T,C] f32 -> spike f16 bits in s1:[T,B,C].
// ---------------------------------------------------------------------------
__global__ __launch_bounds__(256) void dw_bn_lif(
    const float* __restrict__ p, const float* __restrict__ dw_w,
    const float* __restrict__ dw_b, const float* __restrict__ gam,
    const float* __restrict__ bet, const float* __restrict__ mu,
    const float* __restrict__ var, ushort* __restrict__ s1) {
  int gid = blockIdx.x * blockDim.x + threadIdx.x;
  int b = gid >> 10;
  int o = gid & 1023;

  float w[7];
#pragma unroll
  for (int k = 0; k < 7; ++k) w[k] = dw_w[o * 7 + k];
  float db = dw_b[o];
  float inv = (float)((double)gam[o] / sqrt((double)var[o] + 1e-5));
  float add = (float)((double)bet[o] - (double)mu[o] * (double)inv);

  const float* pp = p + (size_t)b * T_ * C_ + o;
  float win[14];
  win[0] = 0.f; win[1] = 0.f; win[2] = 0.f;
#pragma unroll
  for (int i = 0; i < 11; ++i) win[3 + i] = pp[(size_t)i * C_];

  float v = 0.f;
  size_t obase = (size_t)b * C_ + o;
  for (int c = 0; c < T_ / 8; ++c) {
    int t0 = c * 8;
    float nx[8];
#pragma unroll
    for (int j = 0; j < 8; ++j) {
      int tn = t0 + 11 + j;
      nx[j] = (tn < T_) ? pp[(size_t)tn * C_] : 0.f;
    }
#pragma unroll
    for (int s = 0; s < 8; ++s) {
      float u = db;
#pragma unroll
      for (int k = 0; k < 7; ++k) u = fmaf(w[k], win[s + k], u);
      u = fmaf(u, inv, add);
      v = fmaf(0.5f, v, u);
      bool sp = (v - 1.0f) >= 0.0f;
      s1[obase + (size_t)(t0 + s) * BCEL] = sp ? (ushort)0x3C00 : (ushort)0;
      v = sp ? 0.0f : v;
    }
#pragma unroll
    for (int i = 0; i < 6; ++i) win[i] = win[i + 8];
#pragma unroll
    for (int j = 0; j < 8; ++j) win[6 + j] = nx[j];
  }
}

// ---------------------------------------------------------------------------
// Scaled 2-way f16 split of the linear weights: w ~= w0 + 2^-11 w1s.
// Exact when multiplied by {0,1} spikes (products exact, f32 accum).
// ---------------------------------------------------------------------------
__global__ __launch_bounds__(256) void split_w(
    const float* __restrict__ w, ushort* __restrict__ w0,
    ushort* __restrict__ w1, int n) {
  int i = blockIdx.x * 256 + threadIdx.x;
  if (i >= n) return;
  float x = w[i];
  union { _Float16 h; ushort u; } h0, h1;
  h0.h = (_Float16)x;
  if (fabsf(x) < 6.1035156e-5f) h0.u = 0;   // keep w0 out of f16 subnormals
  float r = x - (float)h0.h;
  h1.h = (_Float16)(r * 2048.0f);
  w0[i] = h0.u;
  w1[i] = h1.u;
}

// ---------------------------------------------------------------------------
// MFMA f16 GEMM, 2-term weight split, single accumulator:
//   y = S*w0^T + (S&0x1000)*w1s^T
// 128x128 tile, BK=32, 4 waves, DOUBLE-BUFFERED LDS (2x24KB), one barrier
// per K-step: stage(next) overlaps MFMA(cur).  LDS XOR-swizzle (rule #21:
// linear global_load_lds dest + inverse-swizzled global SOURCE column +
// swizzled READ column; g(row)=((row>>1)&3)<<4 bytes, involution in-row).
// ---------------------------------------------------------------------------
#define BM 128
#define BN 128
#define BKg 32

__global__ __launch_bounds__(256) void gemm_mfma2p(
    const ushort* __restrict__ A,
    const ushort* __restrict__ B0,
    const ushort* __restrict__ B1,
    float* __restrict__ Cout) {
  const int K = C_;
  const int N = C_;
  // [buf][mat: 0=A,1=B0,2=B1][row*32 + col]
  __shared__ __align__(16) ushort lds[2][3][BM * BKg];   // 48 KB

  const int tid  = threadIdx.x;
  const int lane = tid & 63;
  const int wm = ((tid >> 6) >> 1) * 64;
  const int wn = ((tid >> 6) & 1) * 64;

  // XCD-aware swizzle: 800 blocks -> 100 contiguous per XCD, n fastest
  int lin = blockIdx.x;
  int qq = gridDim.x >> 3;                 // 100
  int wg = (lin & 7) * qq + (lin >> 3);
  const int m0 = (wg >> 3) * BM;
  const int n0 = (wg & 7) * BN;

  // staging: thread covers chunks tid and tid+256 of each 8KB tile
  // chunk c: row=c>>2, col=(c&3)*8 ushorts; source col inverse-swizzled
  const int r0 = tid >> 2, r1 = r0 + 64;
  const int kc = (tid & 3) * 8;
  const int ks = kc ^ (((tid >> 3) & 3) << 3);   // == kc ^ (((r>>1)&3)<<3), same for r0,r1

  // read-side fragment swizzle: row = wm + m*16 + fr  ->  ((row>>1)&3) == ((fr>>1)&3)
  const int fr = lane & 15;
  const int k8 = (lane >> 4) * 8;
  const int k8s = k8 ^ (((fr >> 1) & 3) << 3);

  f32x4 acc[4][4] = {};

#define STAGE(bufi, kk0)                                                       \
  do {                                                                         \
    __builtin_amdgcn_global_load_lds(                                          \
        (const __attribute__((address_space(1))) uint32_t*)(A + (size_t)(m0 + r0) * K + (kk0) + ks),  \
        (__attribute__((address_space(3))) uint32_t*)&lds[bufi][0][tid * 8], 16, 0, 0);               \
    __builtin_amdgcn_global_load_lds(                                          \
        (const __attribute__((address_space(1))) uint32_t*)(A + (size_t)(m0 + r1) * K + (kk0) + ks),  \
        (__attribute__((address_space(3))) uint32_t*)&lds[bufi][0][(tid + 256) * 8], 16, 0, 0);       \
    __builtin_amdgcn_global_load_lds(                                          \
        (const __attribute__((address_space(1))) uint32_t*)(B0 + (size_t)(n0 + r0) * K + (kk0) + ks), \
        (__attribute__((address_space(3))) uint32_t*)&lds[bufi][1][tid * 8], 16, 0, 0);               \
    __builtin_amdgcn_global_load_lds(                                          \
        (const __attribute__((address_space(1))) uint32_t*)(B0 + (size_t)(n0 + r1) * K + (kk0) + ks), \
        (__attribute__((address_space(3))) uint32_t*)&lds[bufi][1][(tid + 256) * 8], 16, 0, 0);       \
    __builtin_amdgcn_global_load_lds(                                          \
        (const __attribute__((address_space(1))) uint32_t*)(B1 + (size_t)(n0 + r0) * K + (kk0) + ks), \
        (__attribute__((address_space(3))) uint32_t*)&lds[bufi][2][tid * 8], 16, 0, 0);               \
    __builtin_amdgcn_global_load_lds(                                          \
        (const __attribute__((address_space(1))) uint32_t*)(B1 + (size_t)(n0 + r1) * K + (kk0) + ks), \
        (__attribute__((address_space(3))) uint32_t*)&lds[bufi][2][(tid + 256) * 8], 16, 0, 0);       \
  } while (0)

  STAGE(0, 0);
  __syncthreads();

  int buf = 0;
  for (int k0 = 0; k0 < K; k0 += BKg) {
    // ---- ds_read current fragments (swizzled columns) ----
    union HU { f16x8 h; u32x4 u; };
    f16x8 af[4], a2f[4], b0f[4], b1f[4];
#pragma unroll
    for (int m = 0; m < 4; ++m) {
      HU t;
      t.h = *(const f16x8*)&lds[buf][0][(wm + m * 16 + fr) * BKg + k8s];
      af[m] = t.h;
      t.u &= 0x10001000u;      // {0,1.0f16} -> {0, 2^-11} exactly
      a2f[m] = t.h;
    }
#pragma unroll
    for (int n = 0; n < 4; ++n) {
      b0f[n] = *(const f16x8*)&lds[buf][1][(wn + n * 16 + fr) * BKg + k8s];
      b1f[n] = *(const f16x8*)&lds[buf][2][(wn + n * 16 + fr) * BKg + k8s];
    }
    // ---- issue next-tile staging; latency hides under the MFMAs ----
    if (k0 + BKg < K) STAGE(buf ^ 1, k0 + BKg);
    // ---- 32 MFMAs ----
#pragma unroll
    for (int m = 0; m < 4; ++m)
#pragma unroll
      for (int n = 0; n < 4; ++n) {
        acc[m][n] = __builtin_amdgcn_mfma_f32_16x16x32_f16(
            af[m], b0f[n], acc[m][n], 0, 0, 0);
        acc[m][n] = __builtin_amdgcn_mfma_f32_16x16x32_f16(
            a2f[m], b1f[n], acc[m][n], 0, 0, 0);
      }
    __syncthreads();   // drains vmcnt (stage) + lgkm; one barrier per K-step
    buf ^= 1;
  }
#undef STAGE

  const int ccol = lane & 15;
  const int crow = (lane >> 4) * 4;
#pragma unroll
  for (int m = 0; m < 4; ++m)
#pragma unroll
    for (int n = 0; n < 4; ++n)
#pragma unroll
      for (int j = 0; j < 4; ++j) {
        int row = m0 + wm + m * 16 + crow + j;
        int col = n0 + wn + n * 16 + ccol;
        Cout[(size_t)row * N + col] = acc[m][n][j];
      }
}

// ---------------------------------------------------------------------------
// BN2 + LIF2 + residual, chunked T by 8 with next-chunk prefetch.
// Safe when y == out (owner-thread read-before-write per element).
// ---------------------------------------------------------------------------
__global__ __launch_bounds__(256) void bn_lif_add(
    const float* __restrict__ y, const ushort* __restrict__ s1b,
    const float* __restrict__ gam, const float* __restrict__ bet,
    const float* __restrict__ mu, const float* __restrict__ var,
    float* __restrict__ out) {
  int gid = blockIdx.x * blockDim.x + threadIdx.x;
  int o = gid & 1023;

  float inv = (float)((double)gam[o] / sqrt((double)var[o] + 1e-5));
  float add = (float)((double)bet[o] - (double)mu[o] * (double)inv);

  float v = 0.f;
  size_t base = (size_t)gid;
  float yv[8]; ushort sv[8];
#pragma unroll
  for (int j = 0; j < 8; ++j) {
    yv[j] = y[base + (size_t)j * BCEL];
    sv[j] = s1b[base + (size_t)j * BCEL];
  }
  for (int c = 0; c < T_ / 8; ++c) {
    int t0 = c * 8;
    float yn[8] = {0,0,0,0,0,0,0,0}; ushort sn[8] = {0,0,0,0,0,0,0,0};
    if (c + 1 < T_ / 8) {
#pragma unroll
      for (int j = 0; j < 8; ++j) {
        size_t idx = base + (size_t)(t0 + 8 + j) * BCEL;
        yn[j] = y[idx];
        sn[j] = s1b[idx];
      }
    }
#pragma unroll
    for (int j = 0; j < 8; ++j) {
      float u = fmaf(yv[j], inv, add);
      v = fmaf(0.5f, v, u);
      bool sp = (v - 1.0f) >= 0.0f;
      float s1v = sv[j] ? 1.0f : 0.0f;
      out[base + (size_t)(t0 + j) * BCEL] = (sp ? 1.0f : 0.0f) + s1v;
      v = sp ? 0.0f : v;
    }
#pragma unroll
    for (int j = 0; j < 8; ++j) { yv[j] = yn[j]; sv[j] = sn[j]; }
  }
}

// ---------------------------------------------------------------------------
extern "C" void kernel_launch(void* const* d_in, const int* in_sizes, int n_in,
                              void* d_out, int out_size, void* d_ws,
                              size_t ws_size, hipStream_t stream) {
  const float* x     = (const float*)d_in[0];
  const float* pw_w  = (const float*)d_in[1];
  const float* pw_b  = (const float*)d_in[2];
  const float* dw_w  = (const float*)d_in[3];
  const float* dw_b  = (const float*)d_in[4];
  const float* bn1g  = (const float*)d_in[5];
  const float* bn1b  = (const float*)d_in[6];
  const float* bn1m  = (const float*)d_in[7];
  const float* bn1v  = (const float*)d_in[8];
  const float* lin_w = (const float*)d_in[9];
  const float* bn2g  = (const float*)d_in[10];
  const float* bn2b  = (const float*)d_in[11];
  const float* bn2m  = (const float*)d_in[12];
  const float* bn2v  = (const float*)d_in[13];

  char* wsb  = (char*)d_ws;
  char* outb = (char*)d_out;
  const size_t PB  = (size_t)M_ * C_ * 4;        // 52,428,800  (p / y, f32)
  const size_t SBB = (size_t)M_ * C_ * 2;        // 26,214,400  (spikes, f16)

  float* p = (float*)d_ws;                       // [B,T,C] f32

  const bool primary = ws_size >= PB + SBB;
  // primary : spikes @ ws+PB, lin-weights @ d_out[0:4MB), y @ ws[0:PB)
  // fallback: spikes @ d_out, memcpy -> ws[0:SBB), weights @ ws+SBB, y @ d_out
  ushort* spikes = primary ? (ushort*)(wsb + PB) : (ushort*)d_out;
  ushort* w0  = primary ? (ushort*)outb : (ushort*)(wsb + SBB);
  ushort* w1s = w0 + (size_t)C_ * C_;
  ushort* Sgemm = primary ? spikes : (ushort*)d_ws;
  float* ybuf = primary ? (float*)d_ws : (float*)d_out;

  // 1) pointwise conv (f32 vector GEMM, exact): p = x . pw_w^T + pw_b
  dim3 pw_grid(M_ / 64, C_ / 64);
  gemm_abt<<<pw_grid, 256, 0, stream>>>(x, pw_w, pw_b, p, M_, C_, CIN_);

  // 2) depthwise + BN1 + LIF1 -> f16 spike bits [T,B,C]
  dw_bn_lif<<<BCEL / 256, 256, 0, stream>>>(p, dw_w, dw_b, bn1g, bn1b, bn1m,
                                            bn1v, spikes);

  // 3) fallback only: move spikes out of d_out before GEMM overwrites it
  if (!primary)
    hipMemcpyAsync(d_ws, d_out, SBB, hipMemcpyDeviceToDevice, stream);

  // 4) linear weight split
  split_w<<<(C_ * C_ + 255) / 256, 256, 0, stream>>>(lin_w, w0, w1s, C_ * C_);

  // 5) linear MFMA GEMM (pipelined + swizzled): y = S.(w0 + 2^-11 w1s)^T
  gemm_mfma2p<<<(M_ / BM) * (C_ / BN), 256, 0, stream>>>(Sgemm, w0, w1s, ybuf);

  // 6) BN2 + LIF2 + residual -> d_out
  bn_lif_add<<<BCEL / 256, 256, 0, stream>>>(ybuf, Sgemm, bn2g, bn2b, bn2m,
                                             bn2v, (float*)d_out);
}